// Round 1
// baseline (419.518 us; speedup 1.0000x reference)
//
#include <hip/hip_runtime.h>
#include <math.h>

static constexpr int Bsz  = 16;
static constexpr int Npts = 2048;
static constexpr int C1 = 64, C2 = 128, C3 = 1024;
static constexpr int NBINS = 73;
static constexpr int NROWS = Bsz * C3;          // 16384
static constexpr int TOTAL = NBINS * NROWS;     // 1196032
static constexpr float VMINf = -10.0f;
static constexpr float TOTAL_MAXf = 327670.0f;  // 20*16384 - 10

__device__ __forceinline__ float bnrelu(float x, float m, float inv, float g, float be) {
    float t = ((x - m) * inv) * g + be;
    return t > 0.0f ? t : 0.0f;
}

// ---------------- conv1: [16,3,2048] -> [16,64,2048] (pre-BN, bias added) ----------------
__global__ __launch_bounds__(256)
void conv1_kernel(const float* __restrict__ x, const float* __restrict__ w,
                  const float* __restrict__ bias, float* __restrict__ out) {
    __shared__ float ws[C1 * 3];
    __shared__ float bs[C1];
    int tid = threadIdx.x;
    if (tid < C1 * 3) ws[tid] = w[tid];
    if (tid < C1) bs[tid] = bias[tid];
    __syncthreads();
    int p = blockIdx.x * 256 + tid;
    int b = p / Npts, n = p % Npts;
    float x0 = x[(b * 3 + 0) * Npts + n];
    float x1 = x[(b * 3 + 1) * Npts + n];
    float x2 = x[(b * 3 + 2) * Npts + n];
    float* o = out + (size_t)b * C1 * Npts + n;
    #pragma unroll
    for (int c = 0; c < C1; ++c) {
        o[(size_t)c * Npts] =
            fmaf(ws[c * 3 + 0], x0, fmaf(ws[c * 3 + 1], x1, fmaf(ws[c * 3 + 2], x2, bs[c])));
    }
}

// ---------------- per-channel mean / rsqrt(var+eps) over (B, N) ----------------
__global__ __launch_bounds__(256)
void stats_kernel(const float* __restrict__ in, int C,
                  float* __restrict__ mout, float* __restrict__ iout) {
    int c = blockIdx.x;
    int tid = threadIdx.x;
    double s = 0.0, ss = 0.0;
    for (int b = 0; b < Bsz; ++b) {
        const float* p = in + ((size_t)b * C + c) * Npts;
        for (int n = tid; n < Npts; n += 256) {
            double v = (double)p[n];
            s += v; ss += v * v;
        }
    }
    __shared__ double sh_s[256];
    __shared__ double sh_q[256];
    sh_s[tid] = s; sh_q[tid] = ss;
    __syncthreads();
    for (int off = 128; off > 0; off >>= 1) {
        if (tid < off) { sh_s[tid] += sh_s[tid + off]; sh_q[tid] += sh_q[tid + off]; }
        __syncthreads();
    }
    if (tid == 0) {
        double cnt = (double)Bsz * (double)Npts;
        double m = sh_s[0] / cnt;
        double var = sh_q[0] / cnt - m * m;
        mout[c] = (float)m;
        iout[c] = (float)(1.0 / sqrt(var + 1e-5));
    }
}

// ---------------- tiled conv (k=1 == GEMM) with BN+ReLU applied to INPUT ----------------
// out[b][o][n] = sum_c W[o][c] * bnrelu(in[b][c][n]) + bias[o]
template<int CIN, int COUT>
__global__ __launch_bounds__(256)
void conv_bn_kernel(const float* __restrict__ in, const float* __restrict__ W,
                    const float* __restrict__ bias,
                    const float* __restrict__ m, const float* __restrict__ inv,
                    const float* __restrict__ g, const float* __restrict__ be,
                    float* __restrict__ out) {
    constexpr int OT = 64, NT = 64, KT = 32;
    __shared__ float Ws[KT][OT];
    __shared__ float Xs[KT][NT];
    int tid = threadIdx.x;
    int nBase = blockIdx.x * NT;
    int oBase = blockIdx.y * OT;
    int b = blockIdx.z;
    int ty = tid / 16, tx = tid % 16;
    float acc[4][4] = {};

    int w_o  = tid / 4;            // 0..63
    int w_k0 = (tid % 4) * 8;      // 0,8,16,24
    int x_c  = tid / 8;            // 0..31
    int x_n0 = (tid % 8) * 8;      // 0..56

    for (int kBase = 0; kBase < CIN; kBase += KT) {
        // W tile -> Ws[k][o] (transposed)
        const float* wp = W + (size_t)(oBase + w_o) * CIN + kBase + w_k0;
        float4 wa = *(const float4*)wp;
        float4 wb = *(const float4*)(wp + 4);
        float wv[8] = {wa.x, wa.y, wa.z, wa.w, wb.x, wb.y, wb.z, wb.w};
        #pragma unroll
        for (int i = 0; i < 8; ++i) Ws[w_k0 + i][w_o] = wv[i];

        // X tile with bn+relu -> Xs[c][n]
        int c = kBase + x_c;
        float mm = m[c], ii = inv[c], gg = g[c], bb = be[c];
        const float* xp = in + ((size_t)b * CIN + c) * Npts + nBase + x_n0;
        float4 xa = *(const float4*)xp;
        float4 xb = *(const float4*)(xp + 4);
        float xv[8] = {xa.x, xa.y, xa.z, xa.w, xb.x, xb.y, xb.z, xb.w};
        #pragma unroll
        for (int i = 0; i < 8; ++i) Xs[x_c][x_n0 + i] = bnrelu(xv[i], mm, ii, gg, bb);

        __syncthreads();
        #pragma unroll
        for (int kk = 0; kk < KT; ++kk) {
            float4 w4 = *(const float4*)(&Ws[kk][ty * 4]);
            float4 x4 = *(const float4*)(&Xs[kk][tx * 4]);
            float wr[4] = {w4.x, w4.y, w4.z, w4.w};
            float xr[4] = {x4.x, x4.y, x4.z, x4.w};
            #pragma unroll
            for (int i = 0; i < 4; ++i)
                #pragma unroll
                for (int j = 0; j < 4; ++j)
                    acc[i][j] = fmaf(wr[i], xr[j], acc[i][j]);
        }
        __syncthreads();
    }

    #pragma unroll
    for (int i = 0; i < 4; ++i) {
        int o = oBase + ty * 4 + i;
        float bv = bias[o];
        float4 r = make_float4(acc[i][0] + bv, acc[i][1] + bv, acc[i][2] + bv, acc[i][3] + bv);
        *(float4*)(out + ((size_t)b * COUT + o) * Npts + nBase + tx * 4) = r;
    }
}

// ---------------- histogram with torch-histc offset-trick semantics ----------------
__global__ __launch_bounds__(256)
void hist_kernel(const float* __restrict__ h3,
                 const float* __restrict__ m, const float* __restrict__ inv,
                 const float* __restrict__ g, const float* __restrict__ be,
                 unsigned* __restrict__ counts) {
    __shared__ unsigned bins[NBINS];
    int row = blockIdx.x;            // b*C3 + f
    int f = row & (C3 - 1);
    int tid = threadIdx.x;
    if (tid < NBINS) bins[tid] = 0u;
    __syncthreads();
    float mm = m[f], ii = inv[f], gg = g[f], bb = be[f];
    float off = 20.0f * (float)row;  // exact in f32 (< 2^19)
    const float* p = h3 + (size_t)row * Npts;
    const float WIDTH = (float)(327680.0 / 1196032.0);
    int rbase = row * NBINS;
    for (int n = tid; n < Npts; n += 256) {
        float v = bnrelu(p[n], mm, ii, gg, bb);
        unsigned long long zmask = __ballot(v == 0.0f);
        if (v == 0.0f) {
            // zeros land exactly in local bin 36: floor(73*row + 36.5)
            int lane = tid & 63;
            if (lane == (int)(__ffsll((unsigned long long)zmask) - 1))
                atomicAdd(&bins[36], (unsigned)__popcll(zmask));
        } else {
            float flat = v + off;
            if (flat >= VMINf && flat <= TOTAL_MAXf) {
                int idx = (int)floorf((flat - VMINf) / WIDTH);
                if (idx > TOTAL - 1) idx = TOTAL - 1;
                if (idx < 0) idx = 0;
                int local = idx - rbase;
                if (local >= 0 && local < NBINS) atomicAdd(&bins[local], 1u);
                else atomicAdd(&counts[idx], 1u);   // faithful spill into neighbor rows
            }
        }
    }
    __syncthreads();
    if (tid < NBINS && bins[tid]) atomicAdd(&counts[rbase + tid], bins[tid]);
}

// ---------------- per-row first-max argmax -> feat ----------------
__global__ __launch_bounds__(256)
void argmax_kernel(const unsigned* __restrict__ counts, float* __restrict__ feat) {
    int row = blockIdx.x * 256 + threadIdx.x;
    if (row >= NROWS) return;
    const unsigned* c = counts + (size_t)row * NBINS;
    unsigned best = c[0]; int bi = 0;
    #pragma unroll 8
    for (int i = 1; i < NBINS; ++i) {
        unsigned v = c[i];
        if (v > best) { best = v; bi = i; }
    }
    feat[row] = (float)bi;
}

// ---------------- FC + batch-BN + ReLU (one block per output feature) ----------------
template<int K, int COUT>
__global__ __launch_bounds__(256)
void fc_bn_relu_kernel(const float* __restrict__ in, const float* __restrict__ W,
                       const float* __restrict__ bias,
                       const float* __restrict__ g, const float* __restrict__ be,
                       float* __restrict__ out) {
    int j = blockIdx.x;
    int tid = threadIdx.x;
    int b = tid / 16;
    int l = tid % 16;
    const float* wrow = W + (size_t)j * K;
    const float* xrow = in + (size_t)b * K;
    float s = 0.0f;
    for (int k = l; k < K; k += 16) s = fmaf(xrow[k], wrow[k], s);
    #pragma unroll
    for (int o = 8; o >= 1; o >>= 1) s += __shfl_xor(s, o, 64);
    __shared__ float vals[Bsz];
    __shared__ float stat[2];
    if (l == 0) vals[b] = s + bias[j];
    __syncthreads();
    if (tid == 0) {
        double a = 0.0, q = 0.0;
        for (int i = 0; i < Bsz; ++i) { double v = vals[i]; a += v; q += v * v; }
        double mm = a / Bsz;
        double var = q / Bsz - mm * mm;
        stat[0] = (float)mm;
        stat[1] = (float)(1.0 / sqrt(var + 1e-5));
    }
    __syncthreads();
    if (tid < Bsz) {
        float t = ((vals[tid] - stat[0]) * stat[1]) * g[j] + be[j];
        out[(size_t)tid * COUT + j] = t > 0.0f ? t : 0.0f;
    }
}

// ---------------- fc3 + identity ----------------
__global__ __launch_bounds__(256)
void fc3_kernel(const float* __restrict__ in, const float* __restrict__ W,
                const float* __restrict__ bias, float* __restrict__ out) {
    int t = threadIdx.x;
    if (t >= Bsz * 9) return;
    int b = t / 9, j = t % 9;
    const float* x = in + (size_t)b * 256;
    const float* w = W + (size_t)j * 256;
    float s = 0.0f;
    for (int k = 0; k < 256; ++k) s = fmaf(x[k], w[k], s);
    s += bias[j];
    if (j == 0 || j == 4 || j == 8) s += 1.0f;
    out[t] = s;
}

extern "C" void kernel_launch(void* const* d_in, const int* in_sizes, int n_in,
                              void* d_out, int out_size, void* d_ws, size_t ws_size,
                              hipStream_t stream) {
    const float* x   = (const float*)d_in[0];
    const float* w1  = (const float*)d_in[1];
    const float* b1  = (const float*)d_in[2];
    const float* g1  = (const float*)d_in[3];
    const float* be1 = (const float*)d_in[4];
    const float* w2  = (const float*)d_in[5];
    const float* b2  = (const float*)d_in[6];
    const float* g2  = (const float*)d_in[7];
    const float* be2 = (const float*)d_in[8];
    const float* w3  = (const float*)d_in[9];
    const float* b3  = (const float*)d_in[10];
    const float* g3  = (const float*)d_in[11];
    const float* be3 = (const float*)d_in[12];
    const float* fw1 = (const float*)d_in[13];
    const float* fb1 = (const float*)d_in[14];
    const float* g4  = (const float*)d_in[15];
    const float* be4 = (const float*)d_in[16];
    const float* fw2 = (const float*)d_in[17];
    const float* fb2 = (const float*)d_in[18];
    const float* g5  = (const float*)d_in[19];
    const float* be5 = (const float*)d_in[20];
    const float* fw3 = (const float*)d_in[21];
    const float* fb3 = (const float*)d_in[22];

    float* ws = (float*)d_ws;
    float* h1 = ws;                          // 16*64*2048   = 2,097,152
    float* h2 = h1 + (size_t)Bsz * C1 * Npts;        // 4,194,304
    float* h3 = h2 + (size_t)Bsz * C2 * Npts;        // 33,554,432
    float* m1 = h3 + (size_t)Bsz * C3 * Npts;
    float* i1 = m1 + C1;
    float* m2 = i1 + C1;
    float* i2 = m2 + C2;
    float* m3 = i2 + C2;
    float* i3 = m3 + C3;
    float* feat = i3 + C3;                   // 16,384
    float* h4 = feat + NROWS;                // 16*512
    float* h5 = h4 + Bsz * 512;              // 16*256
    unsigned* counts = (unsigned*)(h5 + Bsz * 256);  // 1,196,032 u32

    hipMemsetAsync(counts, 0, (size_t)TOTAL * sizeof(unsigned), stream);

    conv1_kernel<<<dim3(Bsz * Npts / 256), 256, 0, stream>>>(x, w1, b1, h1);
    stats_kernel<<<dim3(C1), 256, 0, stream>>>(h1, C1, m1, i1);
    conv_bn_kernel<C1, C2><<<dim3(Npts / 64, C2 / 64, Bsz), 256, 0, stream>>>(
        h1, w2, b2, m1, i1, g1, be1, h2);
    stats_kernel<<<dim3(C2), 256, 0, stream>>>(h2, C2, m2, i2);
    conv_bn_kernel<C2, C3><<<dim3(Npts / 64, C3 / 64, Bsz), 256, 0, stream>>>(
        h2, w3, b3, m2, i2, g2, be2, h3);
    stats_kernel<<<dim3(C3), 256, 0, stream>>>(h3, C3, m3, i3);
    hist_kernel<<<dim3(NROWS), 256, 0, stream>>>(h3, m3, i3, g3, be3, counts);
    argmax_kernel<<<dim3(NROWS / 256), 256, 0, stream>>>(counts, feat);
    fc_bn_relu_kernel<1024, 512><<<dim3(512), 256, 0, stream>>>(feat, fw1, fb1, g4, be4, h4);
    fc_bn_relu_kernel<512, 256><<<dim3(256), 256, 0, stream>>>(h4, fw2, fb2, g5, be5, h5);
    fc3_kernel<<<dim3(1), 256, 0, stream>>>(h5, fw3, fb3, (float*)d_out);
}

// Round 6
// 392.289 us; speedup vs baseline: 1.0694x; 1.0694x over previous
//
#include <hip/hip_runtime.h>
#include <math.h>

static constexpr int Bsz  = 16;
static constexpr int Npts = 2048;
static constexpr int C1 = 64, C2 = 128, C3 = 1024;
static constexpr int NBINS = 73;
static constexpr int NROWS = Bsz * C3;          // 16384
static constexpr int TOTAL = NBINS * NROWS;     // 1196032
static constexpr float VMINf = -10.0f;
static constexpr float TOTAL_MAXf = 327670.0f;  // 20*16384 - 10

__device__ __forceinline__ float bnrelu(float x, float m, float inv, float g, float be) {
    float t = ((x - m) * inv) * g + be;
    return t > 0.0f ? t : 0.0f;
}

// ---------------- conv1: [16,3,2048] -> [16,64,2048] (pre-BN, bias added) ----------------
__global__ __launch_bounds__(256)
void conv1_kernel(const float* __restrict__ x, const float* __restrict__ w,
                  const float* __restrict__ bias, float* __restrict__ out) {
    __shared__ float ws[C1 * 3];
    __shared__ float bs[C1];
    int tid = threadIdx.x;
    if (tid < C1 * 3) ws[tid] = w[tid];
    if (tid < C1) bs[tid] = bias[tid];
    __syncthreads();
    int p = blockIdx.x * 256 + tid;
    int b = p / Npts, n = p % Npts;
    float x0 = x[(b * 3 + 0) * Npts + n];
    float x1 = x[(b * 3 + 1) * Npts + n];
    float x2 = x[(b * 3 + 2) * Npts + n];
    float* o = out + (size_t)b * C1 * Npts + n;
    #pragma unroll
    for (int c = 0; c < C1; ++c) {
        o[(size_t)c * Npts] =
            fmaf(ws[c * 3 + 0], x0, fmaf(ws[c * 3 + 1], x1, fmaf(ws[c * 3 + 2], x2, bs[c])));
    }
}

// ---------------- per-channel mean / rsqrt(var+eps) over (B, N) (used for h1 only) ----------------
__global__ __launch_bounds__(256)
void stats_kernel(const float* __restrict__ in, int C,
                  float* __restrict__ mout, float* __restrict__ iout) {
    int c = blockIdx.x;
    int tid = threadIdx.x;
    double s = 0.0, ss = 0.0;
    for (int b = 0; b < Bsz; ++b) {
        const float* p = in + ((size_t)b * C + c) * Npts;
        for (int n = tid; n < Npts; n += 256) {
            double v = (double)p[n];
            s += v; ss += v * v;
        }
    }
    __shared__ double sh_s[256];
    __shared__ double sh_q[256];
    sh_s[tid] = s; sh_q[tid] = ss;
    __syncthreads();
    for (int off = 128; off > 0; off >>= 1) {
        if (tid < off) { sh_s[tid] += sh_s[tid + off]; sh_q[tid] += sh_q[tid + off]; }
        __syncthreads();
    }
    if (tid == 0) {
        double cnt = (double)Bsz * (double)Npts;
        double m = sh_s[0] / cnt;
        double var = sh_q[0] / cnt - m * m;
        mout[c] = (float)m;
        iout[c] = (float)(1.0 / sqrt(var + 1e-5));
    }
}

// ---------------- finalize: (sum, sumsq) -> (mean, rsqrt(var+eps)) ----------------
__global__ __launch_bounds__(256)
void finalize_stats_kernel(const double* __restrict__ s, const double* __restrict__ q, int C,
                           float* __restrict__ mout, float* __restrict__ iout) {
    int c = blockIdx.x * 256 + threadIdx.x;
    if (c >= C) return;
    double cnt = (double)Bsz * (double)Npts;
    double m = s[c] / cnt;
    double var = q[c] / cnt - m * m;
    mout[c] = (float)m;
    iout[c] = (float)(1.0 / sqrt(var + 1e-5));
}

// ---------------- 128x128 tiled conv (k=1 GEMM), BN+ReLU on input, fused output stats ----
// out[b][o][n] = sum_c W[o][c] * bnrelu(in[b][c][n]) + bias[o]; also sum/sumsq per o.
template<int CIN, int COUT>
__global__ __launch_bounds__(256)
void conv_bn_128(const float* __restrict__ in, const float* __restrict__ W,
                 const float* __restrict__ bias,
                 const float* __restrict__ m, const float* __restrict__ inv,
                 const float* __restrict__ g, const float* __restrict__ be,
                 float* __restrict__ out,
                 double* __restrict__ sum, double* __restrict__ sumsq) {
    constexpr int KT = 16;
    __shared__ float Ws[KT][128];
    __shared__ float Xs[KT][128];
    const int tid = threadIdx.x;
    const int nBase = blockIdx.x * 128;
    const int oBase = blockIdx.y * 128;
    const int b = blockIdx.z;
    const int ty = tid >> 4, tx = tid & 15;
    const int w_o = tid >> 1, w_k0 = (tid & 1) * 8;
    const int x_c = tid >> 4, x_n0 = (tid & 15) * 8;
    float acc[8][8] = {};

    for (int kBase = 0; kBase < CIN; kBase += KT) {
        const float* wp = W + (size_t)(oBase + w_o) * CIN + kBase + w_k0;
        float4 wa = *(const float4*)wp;
        float4 wb = *(const float4*)(wp + 4);
        int c = kBase + x_c;
        float mm = m[c], ii = inv[c], gg = g[c], bb = be[c];
        const float* xp = in + ((size_t)b * CIN + c) * Npts + nBase + x_n0;
        float4 xa = *(const float4*)xp;
        float4 xb = *(const float4*)(xp + 4);

        Ws[w_k0 + 0][w_o] = wa.x; Ws[w_k0 + 1][w_o] = wa.y;
        Ws[w_k0 + 2][w_o] = wa.z; Ws[w_k0 + 3][w_o] = wa.w;
        Ws[w_k0 + 4][w_o] = wb.x; Ws[w_k0 + 5][w_o] = wb.y;
        Ws[w_k0 + 6][w_o] = wb.z; Ws[w_k0 + 7][w_o] = wb.w;

        float4 s0, s1;
        s0.x = bnrelu(xa.x, mm, ii, gg, bb); s0.y = bnrelu(xa.y, mm, ii, gg, bb);
        s0.z = bnrelu(xa.z, mm, ii, gg, bb); s0.w = bnrelu(xa.w, mm, ii, gg, bb);
        s1.x = bnrelu(xb.x, mm, ii, gg, bb); s1.y = bnrelu(xb.y, mm, ii, gg, bb);
        s1.z = bnrelu(xb.z, mm, ii, gg, bb); s1.w = bnrelu(xb.w, mm, ii, gg, bb);
        *(float4*)&Xs[x_c][x_n0] = s0;
        *(float4*)&Xs[x_c][x_n0 + 4] = s1;

        __syncthreads();
        #pragma unroll
        for (int kk = 0; kk < KT; ++kk) {
            float4 wA = *(const float4*)&Ws[kk][ty * 8];
            float4 wB = *(const float4*)&Ws[kk][ty * 8 + 4];
            float4 xA = *(const float4*)&Xs[kk][tx * 8];
            float4 xB = *(const float4*)&Xs[kk][tx * 8 + 4];
            float wr[8] = {wA.x, wA.y, wA.z, wA.w, wB.x, wB.y, wB.z, wB.w};
            float xr[8] = {xA.x, xA.y, xA.z, xA.w, xB.x, xB.y, xB.z, xB.w};
            #pragma unroll
            for (int i = 0; i < 8; ++i)
                #pragma unroll
                for (int j = 0; j < 8; ++j)
                    acc[i][j] = fmaf(wr[i], xr[j], acc[i][j]);
        }
        __syncthreads();
    }

    #pragma unroll
    for (int i = 0; i < 8; ++i) {
        int o = oBase + ty * 8 + i;
        float bv = bias[o];
        float v[8];
        #pragma unroll
        for (int j = 0; j < 8; ++j) v[j] = acc[i][j] + bv;
        float* op = out + ((size_t)b * COUT + o) * Npts + nBase + tx * 8;
        *(float4*)op       = make_float4(v[0], v[1], v[2], v[3]);
        *(float4*)(op + 4) = make_float4(v[4], v[5], v[6], v[7]);
        double si = 0.0, qi = 0.0;
        #pragma unroll
        for (int j = 0; j < 8; ++j) { double dv = (double)v[j]; si += dv; qi += dv * dv; }
        #pragma unroll
        for (int off = 1; off < 16; off <<= 1) {
            si += __shfl_xor(si, off, 64);
            qi += __shfl_xor(qi, off, 64);
        }
        if (tx == 0) {
            unsafeAtomicAdd(&sum[o], si);
            unsafeAtomicAdd(&sumsq[o], qi);
        }
    }
}

// ---------------- 64x64 tiled conv (for conv2), BN+ReLU on input, fused output stats ----
template<int CIN, int COUT>
__global__ __launch_bounds__(256)
void conv_bn_64(const float* __restrict__ in, const float* __restrict__ W,
                const float* __restrict__ bias,
                const float* __restrict__ m, const float* __restrict__ inv,
                const float* __restrict__ g, const float* __restrict__ be,
                float* __restrict__ out,
                double* __restrict__ sum, double* __restrict__ sumsq) {
    constexpr int KT = 32;
    __shared__ float Ws[KT][64];
    __shared__ float Xs[KT][64];
    int tid = threadIdx.x;
    int nBase = blockIdx.x * 64;
    int oBase = blockIdx.y * 64;
    int b = blockIdx.z;
    int ty = tid / 16, tx = tid % 16;
    float acc[4][4] = {};

    int w_o  = tid / 4;
    int w_k0 = (tid % 4) * 8;
    int x_c  = tid / 8;
    int x_n0 = (tid % 8) * 8;

    for (int kBase = 0; kBase < CIN; kBase += KT) {
        const float* wp = W + (size_t)(oBase + w_o) * CIN + kBase + w_k0;
        float4 wa = *(const float4*)wp;
        float4 wb = *(const float4*)(wp + 4);
        float wv[8] = {wa.x, wa.y, wa.z, wa.w, wb.x, wb.y, wb.z, wb.w};
        #pragma unroll
        for (int i = 0; i < 8; ++i) Ws[w_k0 + i][w_o] = wv[i];

        int c = kBase + x_c;
        float mm = m[c], ii = inv[c], gg = g[c], bb = be[c];
        const float* xp = in + ((size_t)b * CIN + c) * Npts + nBase + x_n0;
        float4 xa = *(const float4*)xp;
        float4 xb = *(const float4*)(xp + 4);
        float xv[8] = {xa.x, xa.y, xa.z, xa.w, xb.x, xb.y, xb.z, xb.w};
        #pragma unroll
        for (int i = 0; i < 8; ++i) Xs[x_c][x_n0 + i] = bnrelu(xv[i], mm, ii, gg, bb);

        __syncthreads();
        #pragma unroll
        for (int kk = 0; kk < KT; ++kk) {
            float4 w4 = *(const float4*)(&Ws[kk][ty * 4]);
            float4 x4 = *(const float4*)(&Xs[kk][tx * 4]);
            float wr[4] = {w4.x, w4.y, w4.z, w4.w};
            float xr[4] = {x4.x, x4.y, x4.z, x4.w};
            #pragma unroll
            for (int i = 0; i < 4; ++i)
                #pragma unroll
                for (int j = 0; j < 4; ++j)
                    acc[i][j] = fmaf(wr[i], xr[j], acc[i][j]);
        }
        __syncthreads();
    }

    #pragma unroll
    for (int i = 0; i < 4; ++i) {
        int o = oBase + ty * 4 + i;
        float bv = bias[o];
        float v[4] = {acc[i][0] + bv, acc[i][1] + bv, acc[i][2] + bv, acc[i][3] + bv};
        *(float4*)(out + ((size_t)b * COUT + o) * Npts + nBase + tx * 4) =
            make_float4(v[0], v[1], v[2], v[3]);
        double si = 0.0, qi = 0.0;
        #pragma unroll
        for (int j = 0; j < 4; ++j) { double dv = (double)v[j]; si += dv; qi += dv * dv; }
        #pragma unroll
        for (int off = 1; off < 16; off <<= 1) {
            si += __shfl_xor(si, off, 64);
            qi += __shfl_xor(qi, off, 64);
        }
        if (tx == 0) {
            unsafeAtomicAdd(&sum[o], si);
            unsafeAtomicAdd(&sumsq[o], qi);
        }
    }
}

// ---------------- histogram with torch-histc offset-trick semantics ----------------
__global__ __launch_bounds__(256)
void hist_kernel(const float* __restrict__ h3,
                 const float* __restrict__ m, const float* __restrict__ inv,
                 const float* __restrict__ g, const float* __restrict__ be,
                 unsigned* __restrict__ counts) {
    __shared__ unsigned bins[NBINS];
    int row = blockIdx.x;            // b*C3 + f
    int f = row & (C3 - 1);
    int tid = threadIdx.x;
    if (tid < NBINS) bins[tid] = 0u;
    __syncthreads();
    float mm = m[f], ii = inv[f], gg = g[f], bb = be[f];
    float off = 20.0f * (float)row;  // exact in f32 (< 2^19)
    const float* p = h3 + (size_t)row * Npts;
    const float WIDTH = (float)(327680.0 / 1196032.0);
    int rbase = row * NBINS;
    for (int n = tid; n < Npts; n += 256) {
        float v = bnrelu(p[n], mm, ii, gg, bb);
        unsigned long long zmask = __ballot(v == 0.0f);
        if (v == 0.0f) {
            int lane = tid & 63;
            if (lane == (int)(__ffsll((unsigned long long)zmask) - 1))
                atomicAdd(&bins[36], (unsigned)__popcll(zmask));
        } else {
            float flat = v + off;
            if (flat >= VMINf && flat <= TOTAL_MAXf) {
                int idx = (int)floorf((flat - VMINf) / WIDTH);
                if (idx > TOTAL - 1) idx = TOTAL - 1;
                if (idx < 0) idx = 0;
                int local = idx - rbase;
                if (local >= 0 && local < NBINS) atomicAdd(&bins[local], 1u);
                else atomicAdd(&counts[idx], 1u);   // faithful spill into neighbor rows
            }
        }
    }
    __syncthreads();
    if (tid < NBINS && bins[tid]) atomicAdd(&counts[rbase + tid], bins[tid]);
}

// ---------------- per-row first-max argmax -> feat ----------------
__global__ __launch_bounds__(256)
void argmax_kernel(const unsigned* __restrict__ counts, float* __restrict__ feat) {
    int row = blockIdx.x * 256 + threadIdx.x;
    if (row >= NROWS) return;
    const unsigned* c = counts + (size_t)row * NBINS;
    unsigned best = c[0]; int bi = 0;
    #pragma unroll 8
    for (int i = 1; i < NBINS; ++i) {
        unsigned v = c[i];
        if (v > best) { best = v; bi = i; }
    }
    feat[row] = (float)bi;
}

// ---------------- FC + batch-BN + ReLU (one block per output feature) ----------------
template<int K, int COUT>
__global__ __launch_bounds__(256)
void fc_bn_relu_kernel(const float* __restrict__ in, const float* __restrict__ W,
                       const float* __restrict__ bias,
                       const float* __restrict__ g, const float* __restrict__ be,
                       float* __restrict__ out) {
    int j = blockIdx.x;
    int tid = threadIdx.x;
    int b = tid / 16;
    int l = tid % 16;
    const float* wrow = W + (size_t)j * K;
    const float* xrow = in + (size_t)b * K;
    float s = 0.0f;
    for (int k = l; k < K; k += 16) s = fmaf(xrow[k], wrow[k], s);
    #pragma unroll
    for (int o = 8; o >= 1; o >>= 1) s += __shfl_xor(s, o, 64);
    __shared__ float vals[Bsz];
    __shared__ float stat[2];
    if (l == 0) vals[b] = s + bias[j];
    __syncthreads();
    if (tid == 0) {
        double a = 0.0, q = 0.0;
        for (int i = 0; i < Bsz; ++i) { double v = vals[i]; a += v; q += v * v; }
        double mm = a / Bsz;
        double var = q / Bsz - mm * mm;
        stat[0] = (float)mm;
        stat[1] = (float)(1.0 / sqrt(var + 1e-5));
    }
    __syncthreads();
    if (tid < Bsz) {
        float t = ((vals[tid] - stat[0]) * stat[1]) * g[j] + be[j];
        out[(size_t)tid * COUT + j] = t > 0.0f ? t : 0.0f;
    }
}

// ---------------- fc3 + identity ----------------
__global__ __launch_bounds__(256)
void fc3_kernel(const float* __restrict__ in, const float* __restrict__ W,
                const float* __restrict__ bias, float* __restrict__ out) {
    int t = threadIdx.x;
    if (t >= Bsz * 9) return;
    int b = t / 9, j = t % 9;
    const float* x = in + (size_t)b * 256;
    const float* w = W + (size_t)j * 256;
    float s = 0.0f;
    for (int k = 0; k < 256; ++k) s = fmaf(x[k], w[k], s);
    s += bias[j];
    if (j == 0 || j == 4 || j == 8) s += 1.0f;
    out[t] = s;
}

extern "C" void kernel_launch(void* const* d_in, const int* in_sizes, int n_in,
                              void* d_out, int out_size, void* d_ws, size_t ws_size,
                              hipStream_t stream) {
    const float* x   = (const float*)d_in[0];
    const float* w1  = (const float*)d_in[1];
    const float* b1  = (const float*)d_in[2];
    const float* g1  = (const float*)d_in[3];
    const float* be1 = (const float*)d_in[4];
    const float* w2  = (const float*)d_in[5];
    const float* b2  = (const float*)d_in[6];
    const float* g2  = (const float*)d_in[7];
    const float* be2 = (const float*)d_in[8];
    const float* w3  = (const float*)d_in[9];
    const float* b3  = (const float*)d_in[10];
    const float* g3  = (const float*)d_in[11];
    const float* be3 = (const float*)d_in[12];
    const float* fw1 = (const float*)d_in[13];
    const float* fb1 = (const float*)d_in[14];
    const float* g4  = (const float*)d_in[15];
    const float* be4 = (const float*)d_in[16];
    const float* fw2 = (const float*)d_in[17];
    const float* fb2 = (const float*)d_in[18];
    const float* g5  = (const float*)d_in[19];
    const float* be5 = (const float*)d_in[20];
    const float* fw3 = (const float*)d_in[21];
    const float* fb3 = (const float*)d_in[22];

    // workspace layout: [f64 accumulators][u32 counts][f32 tensors]
    double* sum2 = (double*)d_ws;                       // 128
    double* q2   = sum2 + C2;                           // 128
    double* sum3 = q2 + C2;                             // 1024
    double* q3   = sum3 + C3;                           // 1024
    unsigned* counts = (unsigned*)(q3 + C3);            // 1,196,032
    float* h1 = (float*)(counts + TOTAL);               // 16*64*2048
    float* h2 = h1 + (size_t)Bsz * C1 * Npts;           // 16*128*2048
    float* h3 = h2 + (size_t)Bsz * C2 * Npts;           // 16*1024*2048
    float* m1 = h3 + (size_t)Bsz * C3 * Npts;
    float* i1 = m1 + C1;
    float* m2 = i1 + C1;
    float* i2 = m2 + C2;
    float* m3 = i2 + C2;
    float* i3 = m3 + C3;
    float* feat = i3 + C3;                              // 16,384
    float* h4 = feat + NROWS;
    float* h5 = h4 + Bsz * 512;

    // zero accumulators + histogram counts in one memset (contiguous)
    size_t zero_bytes = (size_t)(2 * C2 + 2 * C3) * sizeof(double) + (size_t)TOTAL * sizeof(unsigned);
    hipMemsetAsync(d_ws, 0, zero_bytes, stream);

    conv1_kernel<<<dim3(Bsz * Npts / 256), 256, 0, stream>>>(x, w1, b1, h1);
    stats_kernel<<<dim3(C1), 256, 0, stream>>>(h1, C1, m1, i1);
    conv_bn_64<C1, C2><<<dim3(Npts / 64, C2 / 64, Bsz), 256, 0, stream>>>(
        h1, w2, b2, m1, i1, g1, be1, h2, sum2, q2);
    finalize_stats_kernel<<<dim3(1), 256, 0, stream>>>(sum2, q2, C2, m2, i2);
    conv_bn_128<C2, C3><<<dim3(Npts / 128, C3 / 128, Bsz), 256, 0, stream>>>(
        h2, w3, b3, m2, i2, g2, be2, h3, sum3, q3);
    finalize_stats_kernel<<<dim3(C3 / 256), 256, 0, stream>>>(sum3, q3, C3, m3, i3);
    hist_kernel<<<dim3(NROWS), 256, 0, stream>>>(h3, m3, i3, g3, be3, counts);
    argmax_kernel<<<dim3(NROWS / 256), 256, 0, stream>>>(counts, feat);
    fc_bn_relu_kernel<1024, 512><<<dim3(512), 256, 0, stream>>>(feat, fw1, fb1, g4, be4, h4);
    fc_bn_relu_kernel<512, 256><<<dim3(256), 256, 0, stream>>>(h4, fw2, fb2, g5, be5, h5);
    fc3_kernel<<<dim3(1), 256, 0, stream>>>(h5, fw3, fb3, (float*)d_out);
}

// Round 7
// 361.550 us; speedup vs baseline: 1.1603x; 1.0850x over previous
//
#include <hip/hip_runtime.h>
#include <math.h>

static constexpr int Bsz  = 16;
static constexpr int Npts = 2048;
static constexpr int C1 = 64, C2 = 128, C3 = 1024;
static constexpr int NBINS = 73;
static constexpr int NROWS = Bsz * C3;          // 16384
static constexpr int TOTAL = NBINS * NROWS;     // 1196032
static constexpr float VMINf = -10.0f;
static constexpr float TOTAL_MAXf = 327670.0f;  // 20*16384 - 10

__device__ __forceinline__ float bnrelu(float x, float m, float inv, float g, float be) {
    float t = ((x - m) * inv) * g + be;
    return t > 0.0f ? t : 0.0f;
}

// ---------------- conv1: [16,3,2048] -> [16,64,2048] (pre-BN, bias added), float4 ----------------
__global__ __launch_bounds__(256)
void conv1_kernel(const float* __restrict__ x, const float* __restrict__ w,
                  const float* __restrict__ bias, float* __restrict__ out) {
    __shared__ float ws[C1 * 3];
    __shared__ float bs[C1];
    int tid = threadIdx.x;
    if (tid < C1 * 3) ws[tid] = w[tid];
    if (tid < C1) bs[tid] = bias[tid];
    __syncthreads();
    int p = blockIdx.x * 256 + tid;        // quad index, total 16*512 = 8192
    int b = p >> 9;                        // 512 quads per batch
    int nq = p & 511;
    const float* xb = x + (size_t)b * 3 * Npts;
    float4 x0 = ((const float4*)xb)[nq];
    float4 x1 = ((const float4*)(xb + Npts))[nq];
    float4 x2 = ((const float4*)(xb + 2 * Npts))[nq];
    float* o = out + (size_t)b * C1 * Npts + nq * 4;
    #pragma unroll
    for (int c = 0; c < C1; ++c) {
        float w0 = ws[c * 3], w1 = ws[c * 3 + 1], w2 = ws[c * 3 + 2], bv = bs[c];
        float4 r;
        r.x = fmaf(w0, x0.x, fmaf(w1, x1.x, fmaf(w2, x2.x, bv)));
        r.y = fmaf(w0, x0.y, fmaf(w1, x1.y, fmaf(w2, x2.y, bv)));
        r.z = fmaf(w0, x0.z, fmaf(w1, x1.z, fmaf(w2, x2.z, bv)));
        r.w = fmaf(w0, x0.w, fmaf(w1, x1.w, fmaf(w2, x2.w, bv)));
        *(float4*)(o + (size_t)c * Npts) = r;
    }
}

// ---------------- partial stats for h1: grid = C1*4 blocks, f64 atomics ----------------
__global__ __launch_bounds__(256)
void stats_partial_kernel(const float* __restrict__ in,
                          double* __restrict__ sum, double* __restrict__ sumsq) {
    int c = blockIdx.x >> 2;
    int qb = blockIdx.x & 3;
    int tid = threadIdx.x;
    double s = 0.0, q = 0.0;
    for (int bb = qb * 4; bb < qb * 4 + 4; ++bb) {
        const float4* p = (const float4*)(in + ((size_t)bb * C1 + c) * Npts);
        for (int n = tid; n < Npts / 4; n += 256) {
            float4 v = p[n];
            double a0 = v.x, a1 = v.y, a2 = v.z, a3 = v.w;
            s += a0 + a1 + a2 + a3;
            q += a0 * a0 + a1 * a1 + a2 * a2 + a3 * a3;
        }
    }
    __shared__ double sh_s[256];
    __shared__ double sh_q[256];
    sh_s[tid] = s; sh_q[tid] = q;
    __syncthreads();
    for (int off = 128; off > 0; off >>= 1) {
        if (tid < off) { sh_s[tid] += sh_s[tid + off]; sh_q[tid] += sh_q[tid + off]; }
        __syncthreads();
    }
    if (tid == 0) {
        unsafeAtomicAdd(&sum[c], sh_s[0]);
        unsafeAtomicAdd(&sumsq[c], sh_q[0]);
    }
}

// ---------------- finalize: (sum, sumsq) -> (mean, rsqrt(var+eps)) ----------------
__global__ __launch_bounds__(256)
void finalize_stats_kernel(const double* __restrict__ s, const double* __restrict__ q, int C,
                           float* __restrict__ mout, float* __restrict__ iout) {
    int c = blockIdx.x * 256 + threadIdx.x;
    if (c >= C) return;
    double cnt = (double)Bsz * (double)Npts;
    double m = s[c] / cnt;
    double var = q[c] / cnt - m * m;
    mout[c] = (float)m;
    iout[c] = (float)(1.0 / sqrt(var + 1e-5));
}

// ---------------- 128x128 tiled conv (k=1 GEMM), BN+ReLU on input, fused output stats ----
// Split-column micro-tile: thread owns cols tx*4..tx*4+3 and 64+tx*4..64+tx*4+3
// -> all LDS reads/writes are 2-way bank aliasing (free), vs 4-way with tx*8.
template<int CIN, int COUT>
__global__ __launch_bounds__(256, 4)
void conv_bn_128(const float* __restrict__ in, const float* __restrict__ W,
                 const float* __restrict__ bias,
                 const float* __restrict__ m, const float* __restrict__ inv,
                 const float* __restrict__ g, const float* __restrict__ be,
                 float* __restrict__ out,
                 double* __restrict__ sum, double* __restrict__ sumsq) {
    constexpr int KT = 16;
    __shared__ float Ws[KT][128];
    __shared__ float Xs[KT][128];
    const int tid = threadIdx.x;
    const int nBase = blockIdx.x * 128;
    const int oBase = blockIdx.y * 128;
    const int b = blockIdx.z;
    const int ty = tid >> 4, tx = tid & 15;
    const int w_o = tid >> 1, w_k0 = (tid & 1) * 8;
    const int x_c = tid >> 4;              // 0..15
    const int x_nA = (tid & 15) * 4;       // 0..60
    float acc[8][8] = {};

    for (int kBase = 0; kBase < CIN; kBase += KT) {
        const float* wp = W + (size_t)(oBase + w_o) * CIN + kBase + w_k0;
        float4 wa = *(const float4*)wp;
        float4 wb = *(const float4*)(wp + 4);
        int c = kBase + x_c;
        float mm = m[c], ii = inv[c], gg = g[c], bb = be[c];
        const float* xp = in + ((size_t)b * CIN + c) * Npts + nBase;
        float4 xa = *(const float4*)(xp + x_nA);
        float4 xb2 = *(const float4*)(xp + 64 + x_nA);

        Ws[w_k0 + 0][w_o] = wa.x; Ws[w_k0 + 1][w_o] = wa.y;
        Ws[w_k0 + 2][w_o] = wa.z; Ws[w_k0 + 3][w_o] = wa.w;
        Ws[w_k0 + 4][w_o] = wb.x; Ws[w_k0 + 5][w_o] = wb.y;
        Ws[w_k0 + 6][w_o] = wb.z; Ws[w_k0 + 7][w_o] = wb.w;

        float4 s0, s1;
        s0.x = bnrelu(xa.x, mm, ii, gg, bb); s0.y = bnrelu(xa.y, mm, ii, gg, bb);
        s0.z = bnrelu(xa.z, mm, ii, gg, bb); s0.w = bnrelu(xa.w, mm, ii, gg, bb);
        s1.x = bnrelu(xb2.x, mm, ii, gg, bb); s1.y = bnrelu(xb2.y, mm, ii, gg, bb);
        s1.z = bnrelu(xb2.z, mm, ii, gg, bb); s1.w = bnrelu(xb2.w, mm, ii, gg, bb);
        *(float4*)&Xs[x_c][x_nA] = s0;
        *(float4*)&Xs[x_c][64 + x_nA] = s1;

        __syncthreads();
        #pragma unroll
        for (int kk = 0; kk < KT; ++kk) {
            float4 wA = *(const float4*)&Ws[kk][ty * 8];      // broadcast within 16-lane group
            float4 wB = *(const float4*)&Ws[kk][ty * 8 + 4];
            float4 xA = *(const float4*)&Xs[kk][tx * 4];      // 2-way aliasing: free
            float4 xB = *(const float4*)&Xs[kk][64 + tx * 4];
            float wr[8] = {wA.x, wA.y, wA.z, wA.w, wB.x, wB.y, wB.z, wB.w};
            float xr[8] = {xA.x, xA.y, xA.z, xA.w, xB.x, xB.y, xB.z, xB.w};
            #pragma unroll
            for (int i = 0; i < 8; ++i)
                #pragma unroll
                for (int j = 0; j < 8; ++j)
                    acc[i][j] = fmaf(wr[i], xr[j], acc[i][j]);
        }
        __syncthreads();
    }

    #pragma unroll
    for (int i = 0; i < 8; ++i) {
        int o = oBase + ty * 8 + i;
        float bv = bias[o];
        float v[8];
        #pragma unroll
        for (int j = 0; j < 8; ++j) v[j] = acc[i][j] + bv;
        float* op = out + ((size_t)b * COUT + o) * Npts + nBase;
        *(float4*)(op + tx * 4)      = make_float4(v[0], v[1], v[2], v[3]);
        *(float4*)(op + 64 + tx * 4) = make_float4(v[4], v[5], v[6], v[7]);
        double si = 0.0, qi = 0.0;
        #pragma unroll
        for (int j = 0; j < 8; ++j) { double dv = (double)v[j]; si += dv; qi += dv * dv; }
        #pragma unroll
        for (int off = 1; off < 16; off <<= 1) {
            si += __shfl_xor(si, off, 64);
            qi += __shfl_xor(qi, off, 64);
        }
        if (tx == 0) {
            unsafeAtomicAdd(&sum[o], si);
            unsafeAtomicAdd(&sumsq[o], qi);
        }
    }
}

// ---------------- 64x64 tiled conv (for conv2), BN+ReLU on input, fused output stats ----
template<int CIN, int COUT>
__global__ __launch_bounds__(256)
void conv_bn_64(const float* __restrict__ in, const float* __restrict__ W,
                const float* __restrict__ bias,
                const float* __restrict__ m, const float* __restrict__ inv,
                const float* __restrict__ g, const float* __restrict__ be,
                float* __restrict__ out,
                double* __restrict__ sum, double* __restrict__ sumsq) {
    constexpr int KT = 32;
    __shared__ float Ws[KT][64];
    __shared__ float Xs[KT][64];
    int tid = threadIdx.x;
    int nBase = blockIdx.x * 64;
    int oBase = blockIdx.y * 64;
    int b = blockIdx.z;
    int ty = tid / 16, tx = tid % 16;
    float acc[4][4] = {};

    int w_o  = tid / 4;
    int w_k0 = (tid % 4) * 8;
    int x_c  = tid / 8;
    int x_n0 = (tid % 8) * 8;

    for (int kBase = 0; kBase < CIN; kBase += KT) {
        const float* wp = W + (size_t)(oBase + w_o) * CIN + kBase + w_k0;
        float4 wa = *(const float4*)wp;
        float4 wb = *(const float4*)(wp + 4);
        float wv[8] = {wa.x, wa.y, wa.z, wa.w, wb.x, wb.y, wb.z, wb.w};
        #pragma unroll
        for (int i = 0; i < 8; ++i) Ws[w_k0 + i][w_o] = wv[i];

        int c = kBase + x_c;
        float mm = m[c], ii = inv[c], gg = g[c], bb = be[c];
        const float* xp = in + ((size_t)b * CIN + c) * Npts + nBase + x_n0;
        float4 xa = *(const float4*)xp;
        float4 xb = *(const float4*)(xp + 4);
        float xv[8] = {xa.x, xa.y, xa.z, xa.w, xb.x, xb.y, xb.z, xb.w};
        #pragma unroll
        for (int i = 0; i < 8; ++i) Xs[x_c][x_n0 + i] = bnrelu(xv[i], mm, ii, gg, bb);

        __syncthreads();
        #pragma unroll
        for (int kk = 0; kk < KT; ++kk) {
            float4 w4 = *(const float4*)(&Ws[kk][ty * 4]);
            float4 x4 = *(const float4*)(&Xs[kk][tx * 4]);
            float wr[4] = {w4.x, w4.y, w4.z, w4.w};
            float xr[4] = {x4.x, x4.y, x4.z, x4.w};
            #pragma unroll
            for (int i = 0; i < 4; ++i)
                #pragma unroll
                for (int j = 0; j < 4; ++j)
                    acc[i][j] = fmaf(wr[i], xr[j], acc[i][j]);
        }
        __syncthreads();
    }

    #pragma unroll
    for (int i = 0; i < 4; ++i) {
        int o = oBase + ty * 4 + i;
        float bv = bias[o];
        float v[4] = {acc[i][0] + bv, acc[i][1] + bv, acc[i][2] + bv, acc[i][3] + bv};
        *(float4*)(out + ((size_t)b * COUT + o) * Npts + nBase + tx * 4) =
            make_float4(v[0], v[1], v[2], v[3]);
        double si = 0.0, qi = 0.0;
        #pragma unroll
        for (int j = 0; j < 4; ++j) { double dv = (double)v[j]; si += dv; qi += dv * dv; }
        #pragma unroll
        for (int off = 1; off < 16; off <<= 1) {
            si += __shfl_xor(si, off, 64);
            qi += __shfl_xor(qi, off, 64);
        }
        if (tx == 0) {
            unsafeAtomicAdd(&sum[o], si);
            unsafeAtomicAdd(&sumsq[o], qi);
        }
    }
}

// ---------------- histogram: float4 loads, wave-private bins, lazy zero counting ----------------
__global__ __launch_bounds__(256)
void hist_kernel(const float* __restrict__ h3,
                 const float* __restrict__ m, const float* __restrict__ inv,
                 const float* __restrict__ g, const float* __restrict__ be,
                 unsigned* __restrict__ counts) {
    __shared__ unsigned bins[4][80];        // per-wave privatized, padded rows
    int row = blockIdx.x;                   // b*C3 + f
    int f = row & (C3 - 1);
    int tid = threadIdx.x;
    int wv = tid >> 6;
    for (int i = tid; i < 4 * 80; i += 256) ((unsigned*)bins)[i] = 0u;
    __syncthreads();
    float mm = m[f], ii = inv[f], gg = g[f], bb = be[f];
    float off = 20.0f * (float)row;         // exact in f32 (< 2^19)
    const float4* p4 = (const float4*)(h3 + (size_t)row * Npts);
    const float WIDTH = (float)(327680.0 / 1196032.0);
    int rbase = row * NBINS;
    int zc = 0;
    for (int n = tid; n < Npts / 4; n += 256) {
        float4 xv = p4[n];
        float vv[4] = {xv.x, xv.y, xv.z, xv.w};
        #pragma unroll
        for (int j = 0; j < 4; ++j) {
            float v = bnrelu(vv[j], mm, ii, gg, bb);
            if (v == 0.0f) { ++zc; continue; }  // ReLU zeros -> local bin 36 exactly
            float flat = v + off;
            if (flat >= VMINf && flat <= TOTAL_MAXf) {
                int idx = (int)floorf((flat - VMINf) / WIDTH);
                if (idx > TOTAL - 1) idx = TOTAL - 1;
                if (idx < 0) idx = 0;
                int local = idx - rbase;
                if (local >= 0 && local < NBINS) atomicAdd(&bins[wv][local], 1u);
                else atomicAdd(&counts[idx], 1u);   // faithful spill into neighbor rows
            }
        }
    }
    #pragma unroll
    for (int o = 32; o >= 1; o >>= 1) zc += __shfl_xor(zc, o, 64);
    if ((tid & 63) == 0 && zc) atomicAdd(&bins[wv][36], (unsigned)zc);
    __syncthreads();
    if (tid < NBINS) {
        unsigned t = bins[0][tid] + bins[1][tid] + bins[2][tid] + bins[3][tid];
        if (t) atomicAdd(&counts[rbase + tid], t);
    }
}

// ---------------- per-row first-max argmax -> feat ----------------
__global__ __launch_bounds__(256)
void argmax_kernel(const unsigned* __restrict__ counts, float* __restrict__ feat) {
    int row = blockIdx.x * 256 + threadIdx.x;
    if (row >= NROWS) return;
    const unsigned* c = counts + (size_t)row * NBINS;
    unsigned best = c[0]; int bi = 0;
    #pragma unroll 8
    for (int i = 1; i < NBINS; ++i) {
        unsigned v = c[i];
        if (v > best) { best = v; bi = i; }
    }
    feat[row] = (float)bi;
}

// ---------------- FC + batch-BN + ReLU (one block per output feature) ----------------
template<int K, int COUT>
__global__ __launch_bounds__(256)
void fc_bn_relu_kernel(const float* __restrict__ in, const float* __restrict__ W,
                       const float* __restrict__ bias,
                       const float* __restrict__ g, const float* __restrict__ be,
                       float* __restrict__ out) {
    int j = blockIdx.x;
    int tid = threadIdx.x;
    int b = tid / 16;
    int l = tid % 16;
    const float* wrow = W + (size_t)j * K;
    const float* xrow = in + (size_t)b * K;
    float s = 0.0f;
    for (int k = l; k < K; k += 16) s = fmaf(xrow[k], wrow[k], s);
    #pragma unroll
    for (int o = 8; o >= 1; o >>= 1) s += __shfl_xor(s, o, 64);
    __shared__ float vals[Bsz];
    __shared__ float stat[2];
    if (l == 0) vals[b] = s + bias[j];
    __syncthreads();
    if (tid == 0) {
        double a = 0.0, q = 0.0;
        for (int i = 0; i < Bsz; ++i) { double v = vals[i]; a += v; q += v * v; }
        double mm = a / Bsz;
        double var = q / Bsz - mm * mm;
        stat[0] = (float)mm;
        stat[1] = (float)(1.0 / sqrt(var + 1e-5));
    }
    __syncthreads();
    if (tid < Bsz) {
        float t = ((vals[tid] - stat[0]) * stat[1]) * g[j] + be[j];
        out[(size_t)tid * COUT + j] = t > 0.0f ? t : 0.0f;
    }
}

// ---------------- fc3 + identity ----------------
__global__ __launch_bounds__(256)
void fc3_kernel(const float* __restrict__ in, const float* __restrict__ W,
                const float* __restrict__ bias, float* __restrict__ out) {
    int t = threadIdx.x;
    if (t >= Bsz * 9) return;
    int b = t / 9, j = t % 9;
    const float* x = in + (size_t)b * 256;
    const float* w = W + (size_t)j * 256;
    float s = 0.0f;
    for (int k = 0; k < 256; ++k) s = fmaf(x[k], w[k], s);
    s += bias[j];
    if (j == 0 || j == 4 || j == 8) s += 1.0f;
    out[t] = s;
}

extern "C" void kernel_launch(void* const* d_in, const int* in_sizes, int n_in,
                              void* d_out, int out_size, void* d_ws, size_t ws_size,
                              hipStream_t stream) {
    const float* x   = (const float*)d_in[0];
    const float* w1  = (const float*)d_in[1];
    const float* b1  = (const float*)d_in[2];
    const float* g1  = (const float*)d_in[3];
    const float* be1 = (const float*)d_in[4];
    const float* w2  = (const float*)d_in[5];
    const float* b2  = (const float*)d_in[6];
    const float* g2  = (const float*)d_in[7];
    const float* be2 = (const float*)d_in[8];
    const float* w3  = (const float*)d_in[9];
    const float* b3  = (const float*)d_in[10];
    const float* g3  = (const float*)d_in[11];
    const float* be3 = (const float*)d_in[12];
    const float* fw1 = (const float*)d_in[13];
    const float* fb1 = (const float*)d_in[14];
    const float* g4  = (const float*)d_in[15];
    const float* be4 = (const float*)d_in[16];
    const float* fw2 = (const float*)d_in[17];
    const float* fb2 = (const float*)d_in[18];
    const float* g5  = (const float*)d_in[19];
    const float* be5 = (const float*)d_in[20];
    const float* fw3 = (const float*)d_in[21];
    const float* fb3 = (const float*)d_in[22];

    // workspace layout: [f64 accumulators][u32 counts][f32 tensors]
    double* sum1 = (double*)d_ws;                       // 64
    double* q1d  = sum1 + C1;                           // 64
    double* sum2 = q1d + C1;                            // 128
    double* q2   = sum2 + C2;                           // 128
    double* sum3 = q2 + C2;                             // 1024
    double* q3   = sum3 + C3;                           // 1024
    unsigned* counts = (unsigned*)(q3 + C3);            // 1,196,032
    float* h1 = (float*)(counts + TOTAL);               // 16*64*2048
    float* h2 = h1 + (size_t)Bsz * C1 * Npts;           // 16*128*2048
    float* h3 = h2 + (size_t)Bsz * C2 * Npts;           // 16*1024*2048
    float* m1 = h3 + (size_t)Bsz * C3 * Npts;
    float* i1 = m1 + C1;
    float* m2 = i1 + C1;
    float* i2 = m2 + C2;
    float* m3 = i2 + C2;
    float* i3 = m3 + C3;
    float* feat = i3 + C3;                              // 16,384
    float* h4 = feat + NROWS;
    float* h5 = h4 + Bsz * 512;

    // zero accumulators + histogram counts in one memset (contiguous)
    size_t zero_bytes = (size_t)(2 * C1 + 2 * C2 + 2 * C3) * sizeof(double)
                      + (size_t)TOTAL * sizeof(unsigned);
    hipMemsetAsync(d_ws, 0, zero_bytes, stream);

    conv1_kernel<<<dim3(Bsz * Npts / 4 / 256), 256, 0, stream>>>(x, w1, b1, h1);
    stats_partial_kernel<<<dim3(C1 * 4), 256, 0, stream>>>(h1, sum1, q1d);
    finalize_stats_kernel<<<dim3(1), 256, 0, stream>>>(sum1, q1d, C1, m1, i1);
    conv_bn_64<C1, C2><<<dim3(Npts / 64, C2 / 64, Bsz), 256, 0, stream>>>(
        h1, w2, b2, m1, i1, g1, be1, h2, sum2, q2);
    finalize_stats_kernel<<<dim3(1), 256, 0, stream>>>(sum2, q2, C2, m2, i2);
    conv_bn_128<C2, C3><<<dim3(Npts / 128, C3 / 128, Bsz), 256, 0, stream>>>(
        h2, w3, b3, m2, i2, g2, be2, h3, sum3, q3);
    finalize_stats_kernel<<<dim3(C3 / 256), 256, 0, stream>>>(sum3, q3, C3, m3, i3);
    hist_kernel<<<dim3(NROWS), 256, 0, stream>>>(h3, m3, i3, g3, be3, counts);
    argmax_kernel<<<dim3(NROWS / 256), 256, 0, stream>>>(counts, feat);
    fc_bn_relu_kernel<1024, 512><<<dim3(512), 256, 0, stream>>>(feat, fw1, fb1, g4, be4, h4);
    fc_bn_relu_kernel<512, 256><<<dim3(256), 256, 0, stream>>>(h4, fw2, fb2, g5, be5, h5);
    fc3_kernel<<<dim3(1), 256, 0, stream>>>(h5, fw3, fb3, (float*)d_out);
}